// Round 1
// baseline (3043.065 us; speedup 1.0000x reference)
//
#include <hip/hip_runtime.h>
#include <math.h>

#define BSZd 32
#define NTOK 243
#define DIMd 544
#define NH 8
#define HDd 68
#define NSEED 17
#define UPDd 1088   // UP*D
#define UCd 136     // UPD/H
#define MLP1D 2176
#define MLP2D 1088
#define MROWS (BSZd*NTOK)          // 7776
#define BND ((size_t)MROWS*DIMd)   // 4230144

// ---------------- LayerNorm: one block per row (D=544) ----------------
__global__ __launch_bounds__(256) void ln_kernel(const float* __restrict__ x,
        const float* __restrict__ g, const float* __restrict__ bb, float* __restrict__ out) {
    int row = blockIdx.x;
    const float* xr = x + (size_t)row * DIMd;
    float* orow = out + (size_t)row * DIMd;
    int tid = threadIdx.x;
    float e0 = xr[tid];
    float e1 = xr[tid + 256];
    float e2 = (tid < DIMd - 512) ? xr[tid + 512] : 0.f;
    float s  = e0 + e1 + e2;
    float sq = e0*e0 + e1*e1 + e2*e2;
    __shared__ float sa[4], sb[4];
    for (int off = 32; off; off >>= 1) { s += __shfl_down(s, off, 64); sq += __shfl_down(sq, off, 64); }
    int lane = tid & 63, w = tid >> 6;
    if (lane == 0) { sa[w] = s; sb[w] = sq; }
    __syncthreads();
    if (tid == 0) { sa[0] = sa[0]+sa[1]+sa[2]+sa[3]; sb[0] = sb[0]+sb[1]+sb[2]+sb[3]; }
    __syncthreads();
    s = sa[0]; sq = sb[0];
    float mean = s * (1.f / DIMd);
    float var  = sq * (1.f / DIMd) - mean * mean;
    float rstd = rsqrtf(var + 1e-5f);
    orow[tid]       = (e0 - mean) * rstd * g[tid]       + bb[tid];
    orow[tid + 256] = (e1 - mean) * rstd * g[tid + 256] + bb[tid + 256];
    if (tid < DIMd - 512)
        orow[tid + 512] = (e2 - mean) * rstd * g[tid + 512] + bb[tid + 512];
}

// ---------------- GEMM: C(M,N) = act(A(M,K) @ W(N,K)^T + bias) + res ----------------
// 64x64 tile, BK=16, 256 threads, 4x4 micro-tile per thread.
template<int ACT, int HAS_BIAS, int HAS_RES>
__global__ __launch_bounds__(256) void gemm_kernel(
        const float* __restrict__ A, const float* __restrict__ W,
        const float* __restrict__ bias, const float* __restrict__ res,
        float* __restrict__ C, int M, int Nn, int K) {
    __shared__ __align__(16) float As[16][68];  // [k][m], row stride 68 floats = 16B aligned
    __shared__ __align__(16) float Ws[16][68];  // [k][n]
    int tid = threadIdx.x;
    int tx = tid & 15, ty = tid >> 4;
    int m0 = blockIdx.y * 64, n0 = blockIdx.x * 64;
    float acc[4][4] = {};
    int lr = tid >> 2;            // 0..63: tile row
    int lk = (tid & 3) << 2;      // 0,4,8,12: k offset (float4)
    for (int k0 = 0; k0 < K; k0 += 16) {
        float4 av = make_float4(0.f,0.f,0.f,0.f), wv = make_float4(0.f,0.f,0.f,0.f);
        int gm = m0 + lr, gn = n0 + lr, gk = k0 + lk;
        if (gm < M)  av = *(const float4*)(A + (size_t)gm * K + gk);
        if (gn < Nn) wv = *(const float4*)(W + (size_t)gn * K + gk);
        __syncthreads();
        As[lk+0][lr]=av.x; As[lk+1][lr]=av.y; As[lk+2][lr]=av.z; As[lk+3][lr]=av.w;
        Ws[lk+0][lr]=wv.x; Ws[lk+1][lr]=wv.y; Ws[lk+2][lr]=wv.z; Ws[lk+3][lr]=wv.w;
        __syncthreads();
        #pragma unroll
        for (int kk = 0; kk < 16; kk++) {
            float4 a4 = *(const float4*)&As[kk][ty << 2];
            float4 b4 = *(const float4*)&Ws[kk][tx << 2];
            float ar[4] = {a4.x, a4.y, a4.z, a4.w};
            float br[4] = {b4.x, b4.y, b4.z, b4.w};
            #pragma unroll
            for (int i = 0; i < 4; i++)
                #pragma unroll
                for (int j = 0; j < 4; j++)
                    acc[i][j] = fmaf(ar[i], br[j], acc[i][j]);
        }
    }
    #pragma unroll
    for (int i = 0; i < 4; i++) {
        int gm = m0 + (ty << 2) + i;
        if (gm >= M) continue;
        #pragma unroll
        for (int j = 0; j < 4; j++) {
            int gn = n0 + (tx << 2) + j;
            if (gn >= Nn) continue;
            float v = acc[i][j];
            if (HAS_BIAS) v += bias[gn];
            if (ACT == 1) v = 0.5f * v * (1.f + erff(v * 0.70710678118654752f));
            if (HAS_RES)  v += res[(size_t)gm * Nn + gn];
            C[(size_t)gm * Nn + gn] = v;
        }
    }
}

// ---------------- Attention: one block per (b,h,i) ----------------
// qkv layout: (B, N, 3*D) with column (t*H + h)*HD + hd, t in {q,k,v}
__global__ __launch_bounds__(256) void attn_kernel(const float* __restrict__ qkv,
        const float* __restrict__ bt, float* __restrict__ o) {
    int i = blockIdx.x, h = blockIdx.y, b = blockIdx.z;
    int tid = threadIdx.x;
    __shared__ float qs[HDd];
    __shared__ float p[NTOK];
    __shared__ float rbuf[4];
    const size_t R = 3 * DIMd;
    const float* base = qkv + (size_t)b * NTOK * R;
    if (tid < HDd) qs[tid] = base[(size_t)i * R + h * HDd + tid];
    __syncthreads();
    const float scale = 0.121267812518166f;  // 68^-0.5
    float sj = -1e30f;
    if (tid < NTOK) {
        const float* kr = base + (size_t)tid * R + (NH + h) * HDd;
        float d = 0.f;
        #pragma unroll 4
        for (int c = 0; c < HDd; c++) d = fmaf(qs[c], kr[c], d);
        sj = d * scale + bt[h * (2 * NTOK - 1) + (i - tid + NTOK - 1)];
    }
    float m = sj;
    for (int off = 32; off; off >>= 1) m = fmaxf(m, __shfl_down(m, off, 64));
    int lane = tid & 63, w = tid >> 6;
    if (lane == 0) rbuf[w] = m;
    __syncthreads();
    m = fmaxf(fmaxf(rbuf[0], rbuf[1]), fmaxf(rbuf[2], rbuf[3]));
    float e = (tid < NTOK) ? expf(sj - m) : 0.f;
    float ssum = e;
    for (int off = 32; off; off >>= 1) ssum += __shfl_down(ssum, off, 64);
    __syncthreads();
    if (lane == 0) rbuf[w] = ssum;
    __syncthreads();
    float denom = rbuf[0] + rbuf[1] + rbuf[2] + rbuf[3];
    if (tid < NTOK) p[tid] = e / denom;
    __syncthreads();
    if (tid < HDd) {
        const float* vbase = base + (2 * NH + h) * HDd + tid;
        float accv = 0.f;
        #pragma unroll 4
        for (int j = 0; j < NTOK; j++) accv = fmaf(p[j], vbase[(size_t)j * R], accv);
        o[((size_t)(b * NTOK + i)) * DIMd + h * HDd + tid] = accv;
    }
}

// ---------------- Seed attention: a_raw[b,h,f,n] = dot_c(xu[b,f,h,:], s0[n,h,:]) ----------------
__global__ __launch_bounds__(256) void seed_a_kernel(const float* __restrict__ xu,
        const float* __restrict__ s0, float* __restrict__ a) {
    int f = blockIdx.x, b = blockIdx.y;
    __shared__ float xr[UPDd];
    const float* xrow = xu + ((size_t)(b * NTOK + f)) * UPDd;
    for (int i = threadIdx.x; i < UPDd; i += 256) xr[i] = xrow[i];
    __syncthreads();
    int t = threadIdx.x;
    if (t < NH * NSEED) {
        int h = t / NSEED, n = t % NSEED;
        const float* srow = s0 + (size_t)n * UPDd + h * UCd;
        const float* xh = xr + h * UCd;
        float d = 0.f;
        #pragma unroll 4
        for (int c = 0; c < UCd; c++) d = fmaf(xh[c], srow[c], d);
        a[(((size_t)(b * NH + h) * NTOK + f) * NSEED) + n] = d;
    }
}

// softmax over f (243) for each (b,h,n)
__global__ __launch_bounds__(256) void seed_softmax_f(float* __restrict__ a) {
    int n = blockIdx.x, h = blockIdx.y, b = blockIdx.z;
    float* base = a + ((size_t)(b * NH + h) * NTOK) * NSEED + n;
    int f = threadIdx.x;
    __shared__ float rbuf[4];
    float v = (f < NTOK) ? base[(size_t)f * NSEED] : -1e30f;
    float m = v;
    for (int off = 32; off; off >>= 1) m = fmaxf(m, __shfl_down(m, off, 64));
    int lane = f & 63, w = f >> 6;
    if (lane == 0) rbuf[w] = m;
    __syncthreads();
    m = fmaxf(fmaxf(rbuf[0], rbuf[1]), fmaxf(rbuf[2], rbuf[3]));
    float e = (f < NTOK) ? expf(v - m) : 0.f;
    float s = e;
    for (int off = 32; off; off >>= 1) s += __shfl_down(s, off, 64);
    __syncthreads();
    if (lane == 0) rbuf[w] = s;
    __syncthreads();
    float denom = rbuf[0] + rbuf[1] + rbuf[2] + rbuf[3];
    if (f < NTOK) base[(size_t)f * NSEED] = e / denom;
}

__global__ void zero_kernel(float* p, int n) {
    int i = blockIdx.x * blockDim.x + threadIdx.x;
    if (i < n) p[i] = 0.f;
}

// normalize over n (17) per (b,h,f), accumulate mean_attn
__global__ __launch_bounds__(256) void seed_norm_n(float* __restrict__ a, float* __restrict__ mean_attn) {
    __shared__ float acc[NSEED];
    if (threadIdx.x < NSEED) acc[threadIdx.x] = 0.f;
    __syncthreads();
    int h = blockIdx.x, b = blockIdx.y;
    int f = threadIdx.x;
    if (f < NTOK) {
        float* base = a + (((size_t)(b * NH + h) * NTOK + f) * NSEED);
        float vals[NSEED];
        float s = 0.f;
        #pragma unroll
        for (int n = 0; n < NSEED; n++) { vals[n] = base[n]; s += vals[n]; }
        float inv = 1.f / (1e-7f + s);
        #pragma unroll
        for (int n = 0; n < NSEED; n++) {
            float wv = vals[n] * inv;
            base[n] = wv;
            atomicAdd(&acc[n], wv);
        }
    }
    __syncthreads();
    if (threadIdx.x < NSEED)
        atomicAdd(&mean_attn[threadIdx.x], acc[threadIdx.x] * (1.f / (BSZd * NH * NTOK)));
}

// o2[b,f,h*UC+c] = sum_n a[b,h,f,n] * s1[n,h*UC+c]
__global__ __launch_bounds__(256) void seed_o2_kernel(const float* __restrict__ a,
        const float* __restrict__ s1, float* __restrict__ o2) {
    int f = blockIdx.x, b = blockIdx.y;
    __shared__ float ar[NH * NSEED];
    if (threadIdx.x < NH * NSEED) {
        int h = threadIdx.x / NSEED, n = threadIdx.x % NSEED;
        ar[threadIdx.x] = a[(((size_t)(b * NH + h) * NTOK + f) * NSEED) + n];
    }
    __syncthreads();
    float* orow = o2 + ((size_t)(b * NTOK + f)) * UPDd;
    for (int idx = threadIdx.x; idx < UPDd; idx += 256) {
        int h = idx / UCd, c = idx % UCd;
        float d = 0.f;
        #pragma unroll
        for (int n = 0; n < NSEED; n++)
            d = fmaf(ar[h * NSEED + n], s1[(size_t)n * UPDd + h * UCd + c], d);
        orow[idx] = d;
    }
}

extern "C" void kernel_launch(void* const* d_in, const int* in_sizes, int n_in,
                              void* d_out, int out_size, void* d_ws, size_t ws_size,
                              hipStream_t stream) {
    (void)in_sizes; (void)n_in; (void)out_size; (void)ws_size;
    const float* x       = (const float*)d_in[0];
    const float* seed    = (const float*)d_in[1];
    const float* ln1_g   = (const float*)d_in[2];
    const float* ln1_b   = (const float*)d_in[3];
    const float* w_qkv   = (const float*)d_in[4];
    const float* w_proj  = (const float*)d_in[5];
    const float* b_proj  = (const float*)d_in[6];
    const float* b_table = (const float*)d_in[7];
    const float* ln2_g   = (const float*)d_in[8];
    const float* ln2_b   = (const float*)d_in[9];
    const float* mlp_w1  = (const float*)d_in[10];
    const float* mlp_b1  = (const float*)d_in[11];
    const float* mlp_w2  = (const float*)d_in[12];
    const float* mlp_b2  = (const float*)d_in[13];
    const float* eln1_g  = (const float*)d_in[14];
    const float* eln1_b  = (const float*)d_in[15];
    const float* w_trans = (const float*)d_in[16];
    const float* b_trans = (const float*)d_in[17];
    const float* w0      = (const float*)d_in[18];
    const float* b0      = (const float*)d_in[19];
    const float* w1      = (const float*)d_in[20];
    const float* b1      = (const float*)d_in[21];
    const float* w_proj2 = (const float*)d_in[22];
    const float* b_proj2 = (const float*)d_in[23];
    const float* eln2_g  = (const float*)d_in[24];
    const float* eln2_b  = (const float*)d_in[25];
    const float* emlp_w1 = (const float*)d_in[26];
    const float* emlp_b1 = (const float*)d_in[27];
    const float* emlp_w2 = (const float*)d_in[28];
    const float* emlp_b2 = (const float*)d_in[29];

    float* ws = (float*)d_ws;
    // Workspace layout (floats): A[BND] | Cb[BND] | Bb[4*BND] | Eb[B*H*N*NS] | S0 | S1
    // total = 6*BND + 1,057,536 + 2*18,496 = 26,475,392 floats ~= 106 MB
    float* Ab = ws;
    float* Cb = ws + BND;
    float* Bb = ws + 2 * BND;
    float* Eb = ws + 6 * BND;
    float* S0 = Eb + (size_t)BSZd * NH * NTOK * NSEED;
    float* S1 = S0 + (size_t)NSEED * UPDd;
    float* xout = (float*)d_out;
    float* mean_attn = xout + BND;

    dim3 blk(256);
    // 1) h = LN(x)
    ln_kernel<<<MROWS, blk, 0, stream>>>(x, ln1_g, ln1_b, Ab);
    // 2) qkv = h @ w_qkv^T  (no bias)
    gemm_kernel<0,0,0><<<dim3(26,122), blk, 0, stream>>>(Ab, w_qkv, nullptr, nullptr, Bb, MROWS, 3*DIMd, DIMd);
    // 3) attention -> o
    attn_kernel<<<dim3(NTOK,NH,BSZd), blk, 0, stream>>>(Bb, b_table, Ab);
    // 4) x1 = x + o @ w_proj^T + b_proj
    gemm_kernel<0,1,1><<<dim3(9,122), blk, 0, stream>>>(Ab, w_proj, b_proj, x, Cb, MROWS, DIMd, DIMd);
    // 5) h2 = LN(x1)
    ln_kernel<<<MROWS, blk, 0, stream>>>(Cb, ln2_g, ln2_b, Ab);
    // 6) t = gelu(h2 @ mlp_w1^T + b1)
    gemm_kernel<1,1,0><<<dim3(34,122), blk, 0, stream>>>(Ab, mlp_w1, mlp_b1, nullptr, Bb, MROWS, MLP1D, DIMd);
    // 7) x2 = x1 + t @ mlp_w2^T + b2
    gemm_kernel<0,1,1><<<dim3(9,122), blk, 0, stream>>>(Bb, mlp_w2, mlp_b2, Cb, Ab, MROWS, DIMd, MLP1D);
    // 8) h3 = LN(x2)
    ln_kernel<<<MROWS, blk, 0, stream>>>(Ab, eln1_g, eln1_b, Cb);
    // 9) xu = h3 @ w_trans^T + b_trans
    gemm_kernel<0,1,0><<<dim3(17,122), blk, 0, stream>>>(Cb, w_trans, b_trans, nullptr, Bb, MROWS, UPDd, DIMd);
    // 10/11) s0, s1
    gemm_kernel<0,1,0><<<dim3(17,1), blk, 0, stream>>>(seed, w0, b0, nullptr, S0, NSEED, UPDd, DIMd);
    gemm_kernel<0,1,0><<<dim3(17,1), blk, 0, stream>>>(seed, w1, b1, nullptr, S1, NSEED, UPDd, DIMd);
    // 12) a_raw
    seed_a_kernel<<<dim3(NTOK,BSZd), blk, 0, stream>>>(Bb, S0, Eb);
    // 13) softmax over f
    seed_softmax_f<<<dim3(NSEED,NH,BSZd), blk, 0, stream>>>(Eb);
    // 14) zero mean_attn (d_out is poisoned before every call)
    zero_kernel<<<1, 32, 0, stream>>>(mean_attn, NSEED);
    // 15) normalize over n + mean_attn accumulation
    seed_norm_n<<<dim3(NH,BSZd), blk, 0, stream>>>(Eb, mean_attn);
    // 16) o2 = a @ s1
    seed_o2_kernel<<<dim3(NTOK,BSZd), blk, 0, stream>>>(Eb, S1, Bb);
    // 17) x3 = x2 + o2 @ w_proj2^T + b_proj2
    gemm_kernel<0,1,1><<<dim3(9,122), blk, 0, stream>>>(Bb, w_proj2, b_proj2, Ab, Cb, MROWS, DIMd, UPDd);
    // 18) h4 = LN(x3)
    ln_kernel<<<MROWS, blk, 0, stream>>>(Cb, eln2_g, eln2_b, Ab);
    // 19) t2 = gelu(h4 @ emlp_w1^T + b1)
    gemm_kernel<1,1,0><<<dim3(17,122), blk, 0, stream>>>(Ab, emlp_w1, emlp_b1, nullptr, Bb, MROWS, MLP2D, DIMd);
    // 20) x4 = x3 + t2 @ emlp_w2^T + b2 -> d_out
    gemm_kernel<0,1,1><<<dim3(9,122), blk, 0, stream>>>(Bb, emlp_w2, emlp_b2, Cb, xout, MROWS, DIMd, MLP2D);
}

// Round 2
// 2076.895 us; speedup vs baseline: 1.4652x; 1.4652x over previous
//
#include <hip/hip_runtime.h>
#include <math.h>

#define BSZd 32
#define NTOK 243
#define DIMd 544
#define NH 8
#define HDd 68
#define NSEED 17
#define UPDd 1088   // UP*D
#define UCd 136     // UPD/H
#define MLP1D 2176
#define MLP2D 1088
#define MROWS (BSZd*NTOK)          // 7776
#define BND ((size_t)MROWS*DIMd)   // 4230144
#define QKVR (3*DIMd)              // 1632
#define SROW 244                   // padded score row (16B-aligned rows)
#define SBATCH ((size_t)NTOK*SROW) // 59292 floats per (b,h) score matrix

// ---------------- LayerNorm: one block per row (D=544) ----------------
__global__ __launch_bounds__(256) void ln_kernel(const float* __restrict__ x,
        const float* __restrict__ g, const float* __restrict__ bb, float* __restrict__ out) {
    int row = blockIdx.x;
    const float* xr = x + (size_t)row * DIMd;
    float* orow = out + (size_t)row * DIMd;
    int tid = threadIdx.x;
    float e0 = xr[tid];
    float e1 = xr[tid + 256];
    float e2 = (tid < DIMd - 512) ? xr[tid + 512] : 0.f;
    float s  = e0 + e1 + e2;
    float sq = e0*e0 + e1*e1 + e2*e2;
    __shared__ float sa[4], sb[4];
    for (int off = 32; off; off >>= 1) { s += __shfl_down(s, off, 64); sq += __shfl_down(sq, off, 64); }
    int lane = tid & 63, w = tid >> 6;
    if (lane == 0) { sa[w] = s; sb[w] = sq; }
    __syncthreads();
    if (tid == 0) { sa[0] = sa[0]+sa[1]+sa[2]+sa[3]; sb[0] = sb[0]+sb[1]+sb[2]+sb[3]; }
    __syncthreads();
    s = sa[0]; sq = sb[0];
    float mean = s * (1.f / DIMd);
    float var  = sq * (1.f / DIMd) - mean * mean;
    float rstd = rsqrtf(var + 1e-5f);
    orow[tid]       = (e0 - mean) * rstd * g[tid]       + bb[tid];
    orow[tid + 256] = (e1 - mean) * rstd * g[tid + 256] + bb[tid + 256];
    if (tid < DIMd - 512)
        orow[tid + 512] = (e2 - mean) * rstd * g[tid + 512] + bb[tid + 512];
}

// ---------------- GEMM: C(M,N) = act(A(M,K) @ W(N,K)^T + bias) + res ----------------
template<int ACT, int HAS_BIAS, int HAS_RES>
__global__ __launch_bounds__(256) void gemm_kernel(
        const float* __restrict__ A, const float* __restrict__ W,
        const float* __restrict__ bias, const float* __restrict__ res,
        float* __restrict__ C, int M, int Nn, int K) {
    __shared__ __align__(16) float As[16][68];  // [k][m]
    __shared__ __align__(16) float Ws[16][68];  // [k][n]
    int tid = threadIdx.x;
    int tx = tid & 15, ty = tid >> 4;
    int m0 = blockIdx.y * 64, n0 = blockIdx.x * 64;
    float acc[4][4] = {};
    int lr = tid >> 2;
    int lk = (tid & 3) << 2;
    for (int k0 = 0; k0 < K; k0 += 16) {
        float4 av = make_float4(0.f,0.f,0.f,0.f), wv = make_float4(0.f,0.f,0.f,0.f);
        int gm = m0 + lr, gn = n0 + lr, gk = k0 + lk;
        if (gm < M)  av = *(const float4*)(A + (size_t)gm * K + gk);
        if (gn < Nn) wv = *(const float4*)(W + (size_t)gn * K + gk);
        __syncthreads();
        As[lk+0][lr]=av.x; As[lk+1][lr]=av.y; As[lk+2][lr]=av.z; As[lk+3][lr]=av.w;
        Ws[lk+0][lr]=wv.x; Ws[lk+1][lr]=wv.y; Ws[lk+2][lr]=wv.z; Ws[lk+3][lr]=wv.w;
        __syncthreads();
        #pragma unroll
        for (int kk = 0; kk < 16; kk++) {
            float4 a4 = *(const float4*)&As[kk][ty << 2];
            float4 b4 = *(const float4*)&Ws[kk][tx << 2];
            float ar[4] = {a4.x, a4.y, a4.z, a4.w};
            float br[4] = {b4.x, b4.y, b4.z, b4.w};
            #pragma unroll
            for (int i = 0; i < 4; i++)
                #pragma unroll
                for (int j = 0; j < 4; j++)
                    acc[i][j] = fmaf(ar[i], br[j], acc[i][j]);
        }
    }
    #pragma unroll
    for (int i = 0; i < 4; i++) {
        int gm = m0 + (ty << 2) + i;
        if (gm >= M) continue;
        #pragma unroll
        for (int j = 0; j < 4; j++) {
            int gn = n0 + (tx << 2) + j;
            if (gn >= Nn) continue;
            float v = acc[i][j];
            if (HAS_BIAS) v += bias[gn];
            if (ACT == 1) v = 0.5f * v * (1.f + erff(v * 0.70710678118654752f));
            if (HAS_RES)  v += res[(size_t)gm * Nn + gn];
            C[(size_t)gm * Nn + gn] = v;
        }
    }
}

// ---------------- Attention pass 1: S = Q@K^T * scale + bias (batched 64x64 tiles) ----
__global__ __launch_bounds__(256) void attn_score(const float* __restrict__ qkv,
        const float* __restrict__ bt, float* __restrict__ S, int pass0) {
    int batch = pass0 + blockIdx.z;
    int b = batch >> 3, h = batch & 7;
    const float* A = qkv + (size_t)b * NTOK * QKVR + h * HDd;        // Q rows, stride QKVR
    const float* W = qkv + (size_t)b * NTOK * QKVR + (NH + h) * HDd; // K rows, stride QKVR
    float* C = S + (size_t)blockIdx.z * SBATCH;
    __shared__ __align__(16) float As[16][68];
    __shared__ __align__(16) float Ws[16][68];
    int tid = threadIdx.x;
    int tx = tid & 15, ty = tid >> 4;
    int m0 = blockIdx.y * 64, n0 = blockIdx.x * 64;
    float acc[4][4] = {};
    int lr = tid >> 2, lk = (tid & 3) << 2;
    for (int k0 = 0; k0 < HDd; k0 += 16) {
        float4 av = make_float4(0.f,0.f,0.f,0.f), wv = make_float4(0.f,0.f,0.f,0.f);
        int gm = m0 + lr, gn = n0 + lr, gk = k0 + lk;
        if (gm < NTOK && gk < HDd) av = *(const float4*)(A + (size_t)gm * QKVR + gk);
        if (gn < NTOK && gk < HDd) wv = *(const float4*)(W + (size_t)gn * QKVR + gk);
        __syncthreads();
        As[lk+0][lr]=av.x; As[lk+1][lr]=av.y; As[lk+2][lr]=av.z; As[lk+3][lr]=av.w;
        Ws[lk+0][lr]=wv.x; Ws[lk+1][lr]=wv.y; Ws[lk+2][lr]=wv.z; Ws[lk+3][lr]=wv.w;
        __syncthreads();
        #pragma unroll
        for (int kk = 0; kk < 16; kk++) {
            float4 a4 = *(const float4*)&As[kk][ty << 2];
            float4 b4 = *(const float4*)&Ws[kk][tx << 2];
            float ar[4] = {a4.x, a4.y, a4.z, a4.w};
            float br[4] = {b4.x, b4.y, b4.z, b4.w};
            #pragma unroll
            for (int i = 0; i < 4; i++)
                #pragma unroll
                for (int j = 0; j < 4; j++)
                    acc[i][j] = fmaf(ar[i], br[j], acc[i][j]);
        }
    }
    const float scale = 0.121267812518166f;  // 68^-0.5
    #pragma unroll
    for (int i = 0; i < 4; i++) {
        int gm = m0 + (ty << 2) + i;
        if (gm >= NTOK) continue;
        #pragma unroll
        for (int j = 0; j < 4; j++) {
            int gn = n0 + (tx << 2) + j;
            if (gn >= NTOK) continue;
            C[(size_t)gm * SROW + gn] = acc[i][j] * scale + bt[h * (2 * NTOK - 1) + gm - gn + NTOK - 1];
        }
    }
}

// ---------------- Attention pass 2: row softmax (row length 243, pad col -> 0) ------
__global__ __launch_bounds__(256) void attn_softmax(float* __restrict__ S) {
    float* row = S + (size_t)blockIdx.y * SBATCH + (size_t)blockIdx.x * SROW;
    int tid = threadIdx.x;
    __shared__ float rbuf[4];
    float v = (tid < NTOK) ? row[tid] : -1e30f;
    float m = v;
    for (int off = 32; off; off >>= 1) m = fmaxf(m, __shfl_down(m, off, 64));
    int lane = tid & 63, w = tid >> 6;
    if (lane == 0) rbuf[w] = m;
    __syncthreads();
    m = fmaxf(fmaxf(rbuf[0], rbuf[1]), fmaxf(rbuf[2], rbuf[3]));
    float e = (tid < NTOK) ? expf(v - m) : 0.f;
    float s = e;
    for (int off = 32; off; off >>= 1) s += __shfl_down(s, off, 64);
    __syncthreads();
    if (lane == 0) rbuf[w] = s;
    __syncthreads();
    float denom = rbuf[0] + rbuf[1] + rbuf[2] + rbuf[3];
    if (tid < NTOK) row[tid] = e / denom;
    if (tid == NTOK) row[tid] = 0.f;   // zero the pad column for PV float4 loads
}

// ---------------- Attention pass 3: O = P @ V (batched, B staged [k][n]) ------------
__global__ __launch_bounds__(256) void attn_pv(const float* __restrict__ S,
        const float* __restrict__ qkv, float* __restrict__ o, int pass0) {
    int batch = pass0 + blockIdx.z;
    int b = batch >> 3, h = batch & 7;
    const float* P = S + (size_t)blockIdx.z * SBATCH;
    const float* V = qkv + (size_t)b * NTOK * QKVR + (2 * NH + h) * HDd;
    __shared__ __align__(16) float As[16][68];   // P chunk [k][m]
    __shared__ __align__(16) float Ws[16][68];   // V chunk [k][n]
    int tid = threadIdx.x;
    int tx = tid & 15, ty = tid >> 4;
    int m0 = blockIdx.y * 64, n0 = blockIdx.x * 64;
    float acc[4][4] = {};
    int lr = tid >> 2, lk = (tid & 3) << 2;   // A staging
    int jr = tid >> 4, nf = (tid & 15) << 2;  // W staging: 16 rows x 16 float4
    for (int k0 = 0; k0 < NTOK; k0 += 16) {
        float4 av = make_float4(0.f,0.f,0.f,0.f), wv = make_float4(0.f,0.f,0.f,0.f);
        int gm = m0 + lr, gk = k0 + lk;
        if (gm < NTOK && gk < NTOK) av = *(const float4*)(P + (size_t)gm * SROW + gk);
        int gj = k0 + jr, gn = n0 + nf;
        if (gj < NTOK && gn < HDd) wv = *(const float4*)(V + (size_t)gj * QKVR + gn);
        __syncthreads();
        As[lk+0][lr]=av.x; As[lk+1][lr]=av.y; As[lk+2][lr]=av.z; As[lk+3][lr]=av.w;
        Ws[jr][nf+0]=wv.x; Ws[jr][nf+1]=wv.y; Ws[jr][nf+2]=wv.z; Ws[jr][nf+3]=wv.w;
        __syncthreads();
        #pragma unroll
        for (int kk = 0; kk < 16; kk++) {
            float4 a4 = *(const float4*)&As[kk][ty << 2];
            float4 b4 = *(const float4*)&Ws[kk][tx << 2];
            float ar[4] = {a4.x, a4.y, a4.z, a4.w};
            float br[4] = {b4.x, b4.y, b4.z, b4.w};
            #pragma unroll
            for (int i = 0; i < 4; i++)
                #pragma unroll
                for (int j = 0; j < 4; j++)
                    acc[i][j] = fmaf(ar[i], br[j], acc[i][j]);
        }
    }
    #pragma unroll
    for (int i = 0; i < 4; i++) {
        int gm = m0 + (ty << 2) + i;
        if (gm >= NTOK) continue;
        #pragma unroll
        for (int j = 0; j < 4; j++) {
            int gn = n0 + (tx << 2) + j;
            if (gn >= HDd) continue;
            o[((size_t)(b * NTOK + gm)) * DIMd + h * HDd + gn] = acc[i][j];
        }
    }
}

// ---------------- Seed attention pieces (unchanged) ----------------
__global__ __launch_bounds__(256) void seed_a_kernel(const float* __restrict__ xu,
        const float* __restrict__ s0, float* __restrict__ a) {
    int f = blockIdx.x, b = blockIdx.y;
    __shared__ float xr[UPDd];
    const float* xrow = xu + ((size_t)(b * NTOK + f)) * UPDd;
    for (int i = threadIdx.x; i < UPDd; i += 256) xr[i] = xrow[i];
    __syncthreads();
    int t = threadIdx.x;
    if (t < NH * NSEED) {
        int h = t / NSEED, n = t % NSEED;
        const float* srow = s0 + (size_t)n * UPDd + h * UCd;
        const float* xh = xr + h * UCd;
        float d = 0.f;
        #pragma unroll 4
        for (int c = 0; c < UCd; c++) d = fmaf(xh[c], srow[c], d);
        a[(((size_t)(b * NH + h) * NTOK + f) * NSEED) + n] = d;
    }
}

__global__ __launch_bounds__(256) void seed_softmax_f(float* __restrict__ a) {
    int n = blockIdx.x, h = blockIdx.y, b = blockIdx.z;
    float* base = a + ((size_t)(b * NH + h) * NTOK) * NSEED + n;
    int f = threadIdx.x;
    __shared__ float rbuf[4];
    float v = (f < NTOK) ? base[(size_t)f * NSEED] : -1e30f;
    float m = v;
    for (int off = 32; off; off >>= 1) m = fmaxf(m, __shfl_down(m, off, 64));
    int lane = f & 63, w = f >> 6;
    if (lane == 0) rbuf[w] = m;
    __syncthreads();
    m = fmaxf(fmaxf(rbuf[0], rbuf[1]), fmaxf(rbuf[2], rbuf[3]));
    float e = (f < NTOK) ? expf(v - m) : 0.f;
    float s = e;
    for (int off = 32; off; off >>= 1) s += __shfl_down(s, off, 64);
    __syncthreads();
    if (lane == 0) rbuf[w] = s;
    __syncthreads();
    float denom = rbuf[0] + rbuf[1] + rbuf[2] + rbuf[3];
    if (f < NTOK) base[(size_t)f * NSEED] = e / denom;
}

__global__ void zero_kernel(float* p, int n) {
    int i = blockIdx.x * blockDim.x + threadIdx.x;
    if (i < n) p[i] = 0.f;
}

__global__ __launch_bounds__(256) void seed_norm_n(float* __restrict__ a, float* __restrict__ mean_attn) {
    __shared__ float acc[NSEED];
    if (threadIdx.x < NSEED) acc[threadIdx.x] = 0.f;
    __syncthreads();
    int h = blockIdx.x, b = blockIdx.y;
    int f = threadIdx.x;
    if (f < NTOK) {
        float* base = a + (((size_t)(b * NH + h) * NTOK + f) * NSEED);
        float vals[NSEED];
        float s = 0.f;
        #pragma unroll
        for (int n = 0; n < NSEED; n++) { vals[n] = base[n]; s += vals[n]; }
        float inv = 1.f / (1e-7f + s);
        #pragma unroll
        for (int n = 0; n < NSEED; n++) {
            float wv = vals[n] * inv;
            base[n] = wv;
            atomicAdd(&acc[n], wv);
        }
    }
    __syncthreads();
    if (threadIdx.x < NSEED)
        atomicAdd(&mean_attn[threadIdx.x], acc[threadIdx.x] * (1.f / (BSZd * NH * NTOK)));
}

__global__ __launch_bounds__(256) void seed_o2_kernel(const float* __restrict__ a,
        const float* __restrict__ s1, float* __restrict__ o2) {
    int f = blockIdx.x, b = blockIdx.y;
    __shared__ float ar[NH * NSEED];
    if (threadIdx.x < NH * NSEED) {
        int h = threadIdx.x / NSEED, n = threadIdx.x % NSEED;
        ar[threadIdx.x] = a[(((size_t)(b * NH + h) * NTOK + f) * NSEED) + n];
    }
    __syncthreads();
    float* orow = o2 + ((size_t)(b * NTOK + f)) * UPDd;
    for (int idx = threadIdx.x; idx < UPDd; idx += 256) {
        int h = idx / UCd, c = idx % UCd;
        float d = 0.f;
        #pragma unroll
        for (int n = 0; n < NSEED; n++)
            d = fmaf(ar[h * NSEED + n], s1[(size_t)n * UPDd + h * UCd + c], d);
        orow[idx] = d;
    }
}

extern "C" void kernel_launch(void* const* d_in, const int* in_sizes, int n_in,
                              void* d_out, int out_size, void* d_ws, size_t ws_size,
                              hipStream_t stream) {
    (void)in_sizes; (void)n_in; (void)out_size; (void)ws_size;
    const float* x       = (const float*)d_in[0];
    const float* seed    = (const float*)d_in[1];
    const float* ln1_g   = (const float*)d_in[2];
    const float* ln1_b   = (const float*)d_in[3];
    const float* w_qkv   = (const float*)d_in[4];
    const float* w_proj  = (const float*)d_in[5];
    const float* b_proj  = (const float*)d_in[6];
    const float* b_table = (const float*)d_in[7];
    const float* ln2_g   = (const float*)d_in[8];
    const float* ln2_b   = (const float*)d_in[9];
    const float* mlp_w1  = (const float*)d_in[10];
    const float* mlp_b1  = (const float*)d_in[11];
    const float* mlp_w2  = (const float*)d_in[12];
    const float* mlp_b2  = (const float*)d_in[13];
    const float* eln1_g  = (const float*)d_in[14];
    const float* eln1_b  = (const float*)d_in[15];
    const float* w_trans = (const float*)d_in[16];
    const float* b_trans = (const float*)d_in[17];
    const float* w0      = (const float*)d_in[18];
    const float* b0      = (const float*)d_in[19];
    const float* w1      = (const float*)d_in[20];
    const float* b1      = (const float*)d_in[21];
    const float* w_proj2 = (const float*)d_in[22];
    const float* b_proj2 = (const float*)d_in[23];
    const float* eln2_g  = (const float*)d_in[24];
    const float* eln2_b  = (const float*)d_in[25];
    const float* emlp_w1 = (const float*)d_in[26];
    const float* emlp_b1 = (const float*)d_in[27];
    const float* emlp_w2 = (const float*)d_in[28];
    const float* emlp_b2 = (const float*)d_in[29];

    float* ws = (float*)d_ws;
    // Layout (floats): Ab[BND] | Cb[BND] | Bb[4*BND] | Eb | S0 | S1  (~106 MB, proven)
    // Attention scores live in Bb's slack after qkv: qkv = 7776*1632 = 12,690,432 fl;
    // S/pass = 64*59292 = 3,794,688 fl; 12.69M+3.79M = 16.49M <= 16.92M. 4 passes.
    float* Ab = ws;
    float* Cb = ws + BND;
    float* Bb = ws + 2 * BND;
    float* Sb = Bb + (size_t)MROWS * QKVR;
    float* Eb = ws + 6 * BND;
    float* S0 = Eb + (size_t)BSZd * NH * NTOK * NSEED;
    float* S1 = S0 + (size_t)NSEED * UPDd;
    float* xout = (float*)d_out;
    float* mean_attn = xout + BND;

    dim3 blk(256);
    // 1) h = LN(x)
    ln_kernel<<<MROWS, blk, 0, stream>>>(x, ln1_g, ln1_b, Ab);
    // 2) qkv = h @ w_qkv^T
    gemm_kernel<0,0,0><<<dim3(26,122), blk, 0, stream>>>(Ab, w_qkv, nullptr, nullptr, Bb, MROWS, 3*DIMd, DIMd);
    // 3) attention -> o (Ab), 4 passes of 64 (b,h) batches
    for (int p = 0; p < 4; p++) {
        attn_score<<<dim3(4,4,64), blk, 0, stream>>>(Bb, b_table, Sb, p * 64);
        attn_softmax<<<dim3(NTOK,64), blk, 0, stream>>>(Sb);
        attn_pv<<<dim3(2,4,64), blk, 0, stream>>>(Sb, Bb, Ab, p * 64);
    }
    // 4) x1 = x + o @ w_proj^T + b_proj
    gemm_kernel<0,1,1><<<dim3(9,122), blk, 0, stream>>>(Ab, w_proj, b_proj, x, Cb, MROWS, DIMd, DIMd);
    // 5) h2 = LN(x1)
    ln_kernel<<<MROWS, blk, 0, stream>>>(Cb, ln2_g, ln2_b, Ab);
    // 6) t = gelu(h2 @ mlp_w1^T + b1)
    gemm_kernel<1,1,0><<<dim3(34,122), blk, 0, stream>>>(Ab, mlp_w1, mlp_b1, nullptr, Bb, MROWS, MLP1D, DIMd);
    // 7) x2 = x1 + t @ mlp_w2^T + b2
    gemm_kernel<0,1,1><<<dim3(9,122), blk, 0, stream>>>(Bb, mlp_w2, mlp_b2, Cb, Ab, MROWS, DIMd, MLP1D);
    // 8) h3 = LN(x2)
    ln_kernel<<<MROWS, blk, 0, stream>>>(Ab, eln1_g, eln1_b, Cb);
    // 9) xu = h3 @ w_trans^T + b_trans
    gemm_kernel<0,1,0><<<dim3(17,122), blk, 0, stream>>>(Cb, w_trans, b_trans, nullptr, Bb, MROWS, UPDd, DIMd);
    // 10/11) s0, s1
    gemm_kernel<0,1,0><<<dim3(17,1), blk, 0, stream>>>(seed, w0, b0, nullptr, S0, NSEED, UPDd, DIMd);
    gemm_kernel<0,1,0><<<dim3(17,1), blk, 0, stream>>>(seed, w1, b1, nullptr, S1, NSEED, UPDd, DIMd);
    // 12) a_raw
    seed_a_kernel<<<dim3(NTOK,BSZd), blk, 0, stream>>>(Bb, S0, Eb);
    // 13) softmax over f
    seed_softmax_f<<<dim3(NSEED,NH,BSZd), blk, 0, stream>>>(Eb);
    // 14) zero mean_attn
    zero_kernel<<<1, 32, 0, stream>>>(mean_attn, NSEED);
    // 15) normalize over n + mean_attn
    seed_norm_n<<<dim3(NH,BSZd), blk, 0, stream>>>(Eb, mean_attn);
    // 16) o2 = a @ s1  -> reuse Bb+offset region after xu consumed? xu (Bb) still needed
    //     as input here; write o2 into Bb's tail region (after xu: 7776*1088 = 8.46M fl,
    //     Bb has 16.92M: o2 at Bb+8.46M, 8.46M fl fits exactly)
    {
        float* o2 = Bb + (size_t)MROWS * UPDd;
        seed_o2_kernel<<<dim3(NTOK,BSZd), blk, 0, stream>>>(Eb, S1, o2);
        // 17) x3 = x2 + o2 @ w_proj2^T + b_proj2
        gemm_kernel<0,1,1><<<dim3(9,122), blk, 0, stream>>>(o2, w_proj2, b_proj2, Ab, Cb, MROWS, DIMd, UPDd);
    }
    // 18) h4 = LN(x3)
    ln_kernel<<<MROWS, blk, 0, stream>>>(Cb, eln2_g, eln2_b, Ab);
    // 19) t2 = gelu(h4 @ emlp_w1^T + b1)
    gemm_kernel<1,1,0><<<dim3(17,122), blk, 0, stream>>>(Ab, emlp_w1, emlp_b1, nullptr, Bb, MROWS, MLP2D, DIMd);
    // 20) x4 = x3 + t2 @ emlp_w2^T + b2 -> d_out
    gemm_kernel<0,1,1><<<dim3(9,122), blk, 0, stream>>>(Bb, emlp_w2, emlp_b2, Cb, xout, MROWS, DIMd, MLP2D);
}

// Round 3
// 1030.031 us; speedup vs baseline: 2.9543x; 2.0163x over previous
//
#include <hip/hip_runtime.h>
#include <math.h>
#include <stdint.h>

#define BSZd 32
#define NTOK 243
#define DIMd 544
#define NH 8
#define HDd 68
#define NSEED 17
#define UPDd 1088   // UP*D
#define UCd 136     // UPD/H
#define MLP1D 2176
#define MLP2D 1088
#define MROWS (BSZd*NTOK)          // 7776
#define MPAD 7808                  // 61*128
#define BND ((size_t)MROWS*DIMd)   // 4230144
#define QKVR (3*DIMd)              // 1632
#define SROW 244
#define SBATCH ((size_t)NTOK*SROW)

typedef __bf16 bfx8 __attribute__((ext_vector_type(8)));
typedef __bf16 bfx4 __attribute__((ext_vector_type(4)));
typedef float  fx4  __attribute__((ext_vector_type(4)));

#define GLOAD_LDS(g, l) __builtin_amdgcn_global_load_lds( \
    (__attribute__((address_space(1))) void*)(g), \
    (__attribute__((address_space(3))) void*)(l), 16, 0, 0)

// ---------------- weight fp32 -> bf16 (pad rows [Nreal,grid) with zeros) ---------
__global__ __launch_bounds__(256) void cvt_w(const float* __restrict__ src,
        __bf16* __restrict__ dst, int Nreal, int K) {
    int n = blockIdx.x;
    __bf16* drow = dst + (size_t)n * K;
    if (n < Nreal) {
        const float* srow = src + (size_t)n * K;
        for (int k = threadIdx.x * 4; k < K; k += 1024) {
            float4 v = *(const float4*)(srow + k);
            bfx4 o; o[0]=(__bf16)v.x; o[1]=(__bf16)v.y; o[2]=(__bf16)v.z; o[3]=(__bf16)v.w;
            *(bfx4*)(drow + k) = o;
        }
    } else {
        bfx4 z = {(__bf16)0.f,(__bf16)0.f,(__bf16)0.f,(__bf16)0.f};
        for (int k = threadIdx.x * 4; k < K; k += 1024) *(bfx4*)(drow + k) = z;
    }
}

// ---------------- LayerNorm fp32 -> bf16 ----------------
__global__ __launch_bounds__(256) void ln_kernel(const float* __restrict__ x,
        const float* __restrict__ g, const float* __restrict__ bb, __bf16* __restrict__ out) {
    int row = blockIdx.x;
    const float* xr = x + (size_t)row * DIMd;
    __bf16* orow = out + (size_t)row * DIMd;
    int tid = threadIdx.x;
    float e0 = xr[tid];
    float e1 = xr[tid + 256];
    float e2 = (tid < DIMd - 512) ? xr[tid + 512] : 0.f;
    float s  = e0 + e1 + e2;
    float sq = e0*e0 + e1*e1 + e2*e2;
    __shared__ float sa[4], sb[4];
    for (int off = 32; off; off >>= 1) { s += __shfl_down(s, off, 64); sq += __shfl_down(sq, off, 64); }
    int lane = tid & 63, w = tid >> 6;
    if (lane == 0) { sa[w] = s; sb[w] = sq; }
    __syncthreads();
    if (tid == 0) { sa[0] = sa[0]+sa[1]+sa[2]+sa[3]; sb[0] = sb[0]+sb[1]+sb[2]+sb[3]; }
    __syncthreads();
    s = sa[0]; sq = sb[0];
    float mean = s * (1.f / DIMd);
    float var  = sq * (1.f / DIMd) - mean * mean;
    float rstd = rsqrtf(var + 1e-5f);
    orow[tid]       = (__bf16)((e0 - mean) * rstd * g[tid]       + bb[tid]);
    orow[tid + 256] = (__bf16)((e1 - mean) * rstd * g[tid + 256] + bb[tid + 256]);
    if (tid < DIMd - 512)
        orow[tid + 512] = (__bf16)((e2 - mean) * rstd * g[tid + 512] + bb[tid + 512]);
}

// ---------------- MFMA GEMM: C = act(A @ W^T + bias) + res ----------------
// A[Mpad][K] bf16, W[Npad][K] bf16 (zero-padded). 128x128 tile, BK=32, 4 waves.
// global_load_lds w/ XOR chunk swizzle; mfma_f32_16x16x32_bf16; fp32 epilogue.
template<int ACT, int HAS_BIAS, int HAS_RES, int OUT_BF16>
__global__ __launch_bounds__(256) void mgemm(
        const __bf16* __restrict__ A, const __bf16* __restrict__ W,
        const float* __restrict__ bias, const float* __restrict__ res,
        void* __restrict__ Cv, int M, int Nreal, int K, int Cstride) {
    __shared__ __bf16 As[128 * 32];
    __shared__ __bf16 Bs[128 * 32];
    const int tid = threadIdx.x;
    const int lane = tid & 63, wave = tid >> 6;
    const int m0 = blockIdx.y * 128, n0 = blockIdx.x * 128;
    // staging: lane -> (row r in 16-row group, LDS chunk cp); global chunk c swizzled
    const int r  = lane >> 2, cp = lane & 3;
    const int c  = cp ^ (r & 3) ^ ((r >> 2) & 1);
    const __bf16* Ag0 = A + (size_t)(m0 + wave * 32 + r) * K + c * 8;
    const __bf16* Ag1 = Ag0 + (size_t)16 * K;
    const __bf16* Wg0 = W + (size_t)(n0 + wave * 32 + r) * K + c * 8;
    const __bf16* Wg1 = Wg0 + (size_t)16 * K;
    __bf16* la0 = As + (wave * 32) * 32;
    __bf16* la1 = As + (wave * 32 + 16) * 32;
    __bf16* lb0 = Bs + (wave * 32) * 32;
    __bf16* lb1 = Bs + (wave * 32 + 16) * 32;
    // fragment read indices
    const int fl = lane & 15, q = lane >> 4;
    const int wm = (wave & 1) * 64, wn = (wave >> 1) * 64;
    const int sw = (fl & 3) ^ ((fl >> 2) & 1);   // row-dependent part of swizzle
    fx4 acc[4][4];
    #pragma unroll
    for (int i = 0; i < 4; i++)
        #pragma unroll
        for (int j = 0; j < 4; j++)
            acc[i][j] = (fx4){0.f, 0.f, 0.f, 0.f};

    for (int k0 = 0; k0 < K; k0 += 32) {
        __syncthreads();
        GLOAD_LDS(Ag0 + k0, la0);
        GLOAD_LDS(Ag1 + k0, la1);
        GLOAD_LDS(Wg0 + k0, lb0);
        GLOAD_LDS(Wg1 + k0, lb1);
        __syncthreads();
        bfx8 af[4], bfr[4];
        #pragma unroll
        for (int i = 0; i < 4; i++) {
            int m = wm + i * 16 + fl;
            int u = m * 4 + (q ^ sw);
            af[i] = *(const bfx8*)(As + u * 8);
            int n = wn + i * 16 + fl;
            int v = n * 4 + (q ^ sw);
            bfr[i] = *(const bfx8*)(Bs + v * 8);
        }
        #pragma unroll
        for (int i = 0; i < 4; i++)
            #pragma unroll
            for (int j = 0; j < 4; j++)
                acc[i][j] = __builtin_amdgcn_mfma_f32_16x16x32_bf16(af[i], bfr[j], acc[i][j], 0, 0, 0);
    }

    #pragma unroll
    for (int i = 0; i < 4; i++) {
        #pragma unroll
        for (int v = 0; v < 4; v++) {
            int row = m0 + wm + i * 16 + q * 4 + v;
            if (row >= M) continue;
            #pragma unroll
            for (int j = 0; j < 4; j++) {
                int col = n0 + wn + j * 16 + fl;
                if (col >= Nreal) continue;
                float val = acc[i][j][v];
                if (HAS_BIAS) val += bias[col];
                if (ACT == 1) val = 0.5f * val * (1.f + erff(val * 0.70710678118654752f));
                if (HAS_RES)  val += res[(size_t)row * Cstride + col];
                if (OUT_BF16) ((__bf16*)Cv)[(size_t)row * Cstride + col] = (__bf16)val;
                else          ((float*)Cv)[(size_t)row * Cstride + col] = val;
            }
        }
    }
}

// ---------------- old fp32 GEMM (kept only for tiny seed GEMMs, M=17) ----------------
__global__ __launch_bounds__(256) void gemm32_kernel(
        const float* __restrict__ A, const float* __restrict__ W,
        const float* __restrict__ bias, float* __restrict__ C, int M, int Nn, int K) {
    __shared__ __align__(16) float As[16][68];
    __shared__ __align__(16) float Ws[16][68];
    int tid = threadIdx.x;
    int tx = tid & 15, ty = tid >> 4;
    int m0 = blockIdx.y * 64, n0 = blockIdx.x * 64;
    float acc[4][4] = {};
    int lr = tid >> 2, lk = (tid & 3) << 2;
    for (int k0 = 0; k0 < K; k0 += 16) {
        float4 av = make_float4(0.f,0.f,0.f,0.f), wv = make_float4(0.f,0.f,0.f,0.f);
        int gm = m0 + lr, gn = n0 + lr, gk = k0 + lk;
        if (gm < M)  av = *(const float4*)(A + (size_t)gm * K + gk);
        if (gn < Nn) wv = *(const float4*)(W + (size_t)gn * K + gk);
        __syncthreads();
        As[lk+0][lr]=av.x; As[lk+1][lr]=av.y; As[lk+2][lr]=av.z; As[lk+3][lr]=av.w;
        Ws[lk+0][lr]=wv.x; Ws[lk+1][lr]=wv.y; Ws[lk+2][lr]=wv.z; Ws[lk+3][lr]=wv.w;
        __syncthreads();
        #pragma unroll
        for (int kk = 0; kk < 16; kk++) {
            float4 a4 = *(const float4*)&As[kk][ty << 2];
            float4 b4 = *(const float4*)&Ws[kk][tx << 2];
            float ar[4] = {a4.x, a4.y, a4.z, a4.w};
            float br[4] = {b4.x, b4.y, b4.z, b4.w};
            #pragma unroll
            for (int i = 0; i < 4; i++)
                #pragma unroll
                for (int j = 0; j < 4; j++)
                    acc[i][j] = fmaf(ar[i], br[j], acc[i][j]);
        }
    }
    #pragma unroll
    for (int i = 0; i < 4; i++) {
        int gm = m0 + (ty << 2) + i;
        if (gm >= M) continue;
        #pragma unroll
        for (int j = 0; j < 4; j++) {
            int gn = n0 + (tx << 2) + j;
            if (gn >= Nn) continue;
            C[(size_t)gm * Nn + gn] = acc[i][j] + bias[gn];
        }
    }
}

// ---------------- Attention pass 1: S = Q@K^T * scale + bias (qkv bf16) ----------
__global__ __launch_bounds__(256) void attn_score(const __bf16* __restrict__ qkv,
        const float* __restrict__ bt, float* __restrict__ S, int pass0) {
    int batch = pass0 + blockIdx.z;
    int b = batch >> 3, h = batch & 7;
    const __bf16* A = qkv + (size_t)b * NTOK * QKVR + h * HDd;
    const __bf16* W = qkv + (size_t)b * NTOK * QKVR + (NH + h) * HDd;
    float* C = S + (size_t)blockIdx.z * SBATCH;
    __shared__ __align__(16) float As[16][68];
    __shared__ __align__(16) float Ws[16][68];
    int tid = threadIdx.x;
    int tx = tid & 15, ty = tid >> 4;
    int m0 = blockIdx.y * 64, n0 = blockIdx.x * 64;
    float acc[4][4] = {};
    int lr = tid >> 2, lk = (tid & 3) << 2;
    for (int k0 = 0; k0 < HDd; k0 += 16) {
        float4 av = make_float4(0.f,0.f,0.f,0.f), wv = make_float4(0.f,0.f,0.f,0.f);
        int gm = m0 + lr, gn = n0 + lr, gk = k0 + lk;
        if (gm < NTOK && gk < HDd) {
            bfx4 t = *(const bfx4*)(A + (size_t)gm * QKVR + gk);
            av = make_float4((float)t[0], (float)t[1], (float)t[2], (float)t[3]);
        }
        if (gn < NTOK && gk < HDd) {
            bfx4 t = *(const bfx4*)(W + (size_t)gn * QKVR + gk);
            wv = make_float4((float)t[0], (float)t[1], (float)t[2], (float)t[3]);
        }
        __syncthreads();
        As[lk+0][lr]=av.x; As[lk+1][lr]=av.y; As[lk+2][lr]=av.z; As[lk+3][lr]=av.w;
        Ws[lk+0][lr]=wv.x; Ws[lk+1][lr]=wv.y; Ws[lk+2][lr]=wv.z; Ws[lk+3][lr]=wv.w;
        __syncthreads();
        #pragma unroll
        for (int kk = 0; kk < 16; kk++) {
            float4 a4 = *(const float4*)&As[kk][ty << 2];
            float4 b4 = *(const float4*)&Ws[kk][tx << 2];
            float ar[4] = {a4.x, a4.y, a4.z, a4.w};
            float br[4] = {b4.x, b4.y, b4.z, b4.w};
            #pragma unroll
            for (int i = 0; i < 4; i++)
                #pragma unroll
                for (int j = 0; j < 4; j++)
                    acc[i][j] = fmaf(ar[i], br[j], acc[i][j]);
        }
    }
    const float scale = 0.121267812518166f;
    #pragma unroll
    for (int i = 0; i < 4; i++) {
        int gm = m0 + (ty << 2) + i;
        if (gm >= NTOK) continue;
        #pragma unroll
        for (int j = 0; j < 4; j++) {
            int gn = n0 + (tx << 2) + j;
            if (gn >= NTOK) continue;
            C[(size_t)gm * SROW + gn] = acc[i][j] * scale + bt[h * (2 * NTOK - 1) + gm - gn + NTOK - 1];
        }
    }
}

// ---------------- Attention pass 2: row softmax ----------------
__global__ __launch_bounds__(256) void attn_softmax(float* __restrict__ S) {
    float* row = S + (size_t)blockIdx.y * SBATCH + (size_t)blockIdx.x * SROW;
    int tid = threadIdx.x;
    __shared__ float rbuf[4];
    float v = (tid < NTOK) ? row[tid] : -1e30f;
    float m = v;
    for (int off = 32; off; off >>= 1) m = fmaxf(m, __shfl_down(m, off, 64));
    int lane = tid & 63, w = tid >> 6;
    if (lane == 0) rbuf[w] = m;
    __syncthreads();
    m = fmaxf(fmaxf(rbuf[0], rbuf[1]), fmaxf(rbuf[2], rbuf[3]));
    float e = (tid < NTOK) ? expf(v - m) : 0.f;
    float s = e;
    for (int off = 32; off; off >>= 1) s += __shfl_down(s, off, 64);
    __syncthreads();
    if (lane == 0) rbuf[w] = s;
    __syncthreads();
    float denom = rbuf[0] + rbuf[1] + rbuf[2] + rbuf[3];
    if (tid < NTOK) row[tid] = e / denom;
    if (tid == NTOK) row[tid] = 0.f;
}

// ---------------- Attention pass 3: O = P @ V -> bf16 o ----------------
__global__ __launch_bounds__(256) void attn_pv(const float* __restrict__ S,
        const __bf16* __restrict__ qkv, __bf16* __restrict__ o, int pass0) {
    int batch = pass0 + blockIdx.z;
    int b = batch >> 3, h = batch & 7;
    const float* P = S + (size_t)blockIdx.z * SBATCH;
    const __bf16* V = qkv + (size_t)b * NTOK * QKVR + (2 * NH + h) * HDd;
    __shared__ __align__(16) float As[16][68];
    __shared__ __align__(16) float Ws[16][68];
    int tid = threadIdx.x;
    int tx = tid & 15, ty = tid >> 4;
    int m0 = blockIdx.y * 64, n0 = blockIdx.x * 64;
    float acc[4][4] = {};
    int lr = tid >> 2, lk = (tid & 3) << 2;
    int jr = tid >> 4, nf = (tid & 15) << 2;
    for (int k0 = 0; k0 < NTOK; k0 += 16) {
        float4 av = make_float4(0.f,0.f,0.f,0.f), wv = make_float4(0.f,0.f,0.f,0.f);
        int gm = m0 + lr, gk = k0 + lk;
        if (gm < NTOK && gk < NTOK) av = *(const float4*)(P + (size_t)gm * SROW + gk);
        int gj = k0 + jr, gn = n0 + nf;
        if (gj < NTOK && gn < HDd) {
            bfx4 t = *(const bfx4*)(V + (size_t)gj * QKVR + gn);
            wv = make_float4((float)t[0], (float)t[1], (float)t[2], (float)t[3]);
        }
        __syncthreads();
        As[lk+0][lr]=av.x; As[lk+1][lr]=av.y; As[lk+2][lr]=av.z; As[lk+3][lr]=av.w;
        Ws[jr][nf+0]=wv.x; Ws[jr][nf+1]=wv.y; Ws[jr][nf+2]=wv.z; Ws[jr][nf+3]=wv.w;
        __syncthreads();
        #pragma unroll
        for (int kk = 0; kk < 16; kk++) {
            float4 a4 = *(const float4*)&As[kk][ty << 2];
            float4 b4 = *(const float4*)&Ws[kk][tx << 2];
            float ar[4] = {a4.x, a4.y, a4.z, a4.w};
            float br[4] = {b4.x, b4.y, b4.z, b4.w};
            #pragma unroll
            for (int i = 0; i < 4; i++)
                #pragma unroll
                for (int j = 0; j < 4; j++)
                    acc[i][j] = fmaf(ar[i], br[j], acc[i][j]);
        }
    }
    #pragma unroll
    for (int i = 0; i < 4; i++) {
        int gm = m0 + (ty << 2) + i;
        if (gm >= NTOK) continue;
        #pragma unroll
        for (int j = 0; j < 4; j++) {
            int gn = n0 + (tx << 2) + j;
            if (gn >= HDd) continue;
            o[((size_t)(b * NTOK + gm)) * DIMd + h * HDd + gn] = (__bf16)acc[i][j];
        }
    }
}

// ---------------- Seed attention (xu bf16) ----------------
__global__ __launch_bounds__(256) void seed_a_kernel(const __bf16* __restrict__ xu,
        const float* __restrict__ s0, float* __restrict__ a) {
    int f = blockIdx.x, b = blockIdx.y;
    __shared__ float xr[UPDd];
    const __bf16* xrow = xu + ((size_t)(b * NTOK + f)) * UPDd;
    for (int i = threadIdx.x; i < UPDd; i += 256) xr[i] = (float)xrow[i];
    __syncthreads();
    int t = threadIdx.x;
    if (t < NH * NSEED) {
        int h = t / NSEED, n = t % NSEED;
        const float* srow = s0 + (size_t)n * UPDd + h * UCd;
        const float* xh = xr + h * UCd;
        float d = 0.f;
        #pragma unroll 4
        for (int c2 = 0; c2 < UCd; c2++) d = fmaf(xh[c2], srow[c2], d);
        a[(((size_t)(b * NH + h) * NTOK + f) * NSEED) + n] = d;
    }
}

__global__ __launch_bounds__(256) void seed_softmax_f(float* __restrict__ a) {
    int n = blockIdx.x, h = blockIdx.y, b = blockIdx.z;
    float* base = a + ((size_t)(b * NH + h) * NTOK) * NSEED + n;
    int f = threadIdx.x;
    __shared__ float rbuf[4];
    float v = (f < NTOK) ? base[(size_t)f * NSEED] : -1e30f;
    float m = v;
    for (int off = 32; off; off >>= 1) m = fmaxf(m, __shfl_down(m, off, 64));
    int lane = f & 63, w = f >> 6;
    if (lane == 0) rbuf[w] = m;
    __syncthreads();
    m = fmaxf(fmaxf(rbuf[0], rbuf[1]), fmaxf(rbuf[2], rbuf[3]));
    float e = (f < NTOK) ? expf(v - m) : 0.f;
    float s = e;
    for (int off = 32; off; off >>= 1) s += __shfl_down(s, off, 64);
    __syncthreads();
    if (lane == 0) rbuf[w] = s;
    __syncthreads();
    float denom = rbuf[0] + rbuf[1] + rbuf[2] + rbuf[3];
    if (f < NTOK) base[(size_t)f * NSEED] = e / denom;
}

__global__ void zero_kernel(float* p, int n) {
    int i = blockIdx.x * blockDim.x + threadIdx.x;
    if (i < n) p[i] = 0.f;
}

__global__ __launch_bounds__(256) void seed_norm_n(float* __restrict__ a, float* __restrict__ mean_attn) {
    __shared__ float acc[NSEED];
    if (threadIdx.x < NSEED) acc[threadIdx.x] = 0.f;
    __syncthreads();
    int h = blockIdx.x, b = blockIdx.y;
    int f = threadIdx.x;
    if (f < NTOK) {
        float* base = a + (((size_t)(b * NH + h) * NTOK + f) * NSEED);
        float vals[NSEED];
        float s = 0.f;
        #pragma unroll
        for (int n = 0; n < NSEED; n++) { vals[n] = base[n]; s += vals[n]; }
        float inv = 1.f / (1e-7f + s);
        #pragma unroll
        for (int n = 0; n < NSEED; n++) {
            float wv = vals[n] * inv;
            base[n] = wv;
            atomicAdd(&acc[n], wv);
        }
    }
    __syncthreads();
    if (threadIdx.x < NSEED)
        atomicAdd(&mean_attn[threadIdx.x], acc[threadIdx.x] * (1.f / (BSZd * NH * NTOK)));
}

__global__ __launch_bounds__(256) void seed_o2_kernel(const float* __restrict__ a,
        const float* __restrict__ s1, __bf16* __restrict__ o2) {
    int f = blockIdx.x, b = blockIdx.y;
    __shared__ float ar[NH * NSEED];
    if (threadIdx.x < NH * NSEED) {
        int h = threadIdx.x / NSEED, n = threadIdx.x % NSEED;
        ar[threadIdx.x] = a[(((size_t)(b * NH + h) * NTOK + f) * NSEED) + n];
    }
    __syncthreads();
    __bf16* orow = o2 + ((size_t)(b * NTOK + f)) * UPDd;
    for (int idx = threadIdx.x; idx < UPDd; idx += 256) {
        int h = idx / UCd, c = idx % UCd;
        float d = 0.f;
        #pragma unroll
        for (int n = 0; n < NSEED; n++)
            d = fmaf(ar[h * NSEED + n], s1[(size_t)n * UPDd + h * UCd + c], d);
        orow[idx] = (__bf16)d;
    }
}

extern "C" void kernel_launch(void* const* d_in, const int* in_sizes, int n_in,
                              void* d_out, int out_size, void* d_ws, size_t ws_size,
                              hipStream_t stream) {
    (void)in_sizes; (void)n_in; (void)out_size; (void)ws_size;
    const float* x       = (const float*)d_in[0];
    const float* seed    = (const float*)d_in[1];
    const float* ln1_g   = (const float*)d_in[2];
    const float* ln1_b   = (const float*)d_in[3];
    const float* w_qkv   = (const float*)d_in[4];
    const float* w_proj  = (const float*)d_in[5];
    const float* b_proj  = (const float*)d_in[6];
    const float* b_table = (const float*)d_in[7];
    const float* ln2_g   = (const float*)d_in[8];
    const float* ln2_b   = (const float*)d_in[9];
    const float* mlp_w1  = (const float*)d_in[10];
    const float* mlp_b1  = (const float*)d_in[11];
    const float* mlp_w2  = (const float*)d_in[12];
    const float* mlp_b2  = (const float*)d_in[13];
    const float* eln1_g  = (const float*)d_in[14];
    const float* eln1_b  = (const float*)d_in[15];
    const float* w_trans = (const float*)d_in[16];
    const float* b_trans = (const float*)d_in[17];
    const float* w0      = (const float*)d_in[18];
    const float* b0      = (const float*)d_in[19];
    const float* w1      = (const float*)d_in[20];
    const float* b1      = (const float*)d_in[21];
    const float* w_proj2 = (const float*)d_in[22];
    const float* b_proj2 = (const float*)d_in[23];
    const float* eln2_g  = (const float*)d_in[24];
    const float* eln2_b  = (const float*)d_in[25];
    const float* emlp_w1 = (const float*)d_in[26];
    const float* emlp_b1 = (const float*)d_in[27];
    const float* emlp_w2 = (const float*)d_in[28];
    const float* emlp_b2 = (const float*)d_in[29];

    // ---- workspace layout (bytes), total 104,444,928 <= proven 105.9MB ----
    char* wsb = (char*)d_ws;
    __bf16* Wq  = (__bf16*)(wsb);               // [1664][544]
    __bf16* Wp  = (__bf16*)(wsb + 1810432);     // [640][544]
    __bf16* Wm1 = (__bf16*)(wsb + 2506752);     // [2176][544]
    __bf16* Wm2 = (__bf16*)(wsb + 4874240);     // [640][2176]
    __bf16* Wt  = (__bf16*)(wsb + 7659520);     // [1152][544]
    __bf16* Wp2 = (__bf16*)(wsb + 8912896);     // [640][1088]
    __bf16* We1 = (__bf16*)(wsb + 10305536);    // [1152][544]
    __bf16* We2 = (__bf16*)(wsb + 11558912);    // [640][1088]
    __bf16* Abf = (__bf16*)(wsb + 12951552);    // [7808][544] bf16 activation
    float*  F1  = (float*) (wsb + 21446656);    // [7776][544] fp32 stream
    float*  F2  = (float*) (wsb + 38367232);    // [7776][544] fp32 stream
    char*   RegBig = wsb + 55287808;            // 33,978,368 B, overlaid
    char*   RegS   = wsb + 89266176;            // 15,178,752 B, overlaid
    __bf16* Qkvb = (__bf16*)RegBig;             // [7776][1632]
    __bf16* Tb   = (__bf16*)RegBig;             // [7808][2176]
    __bf16* XU   = (__bf16*)RegBig;             // [7776][1088]
    __bf16* O2   = (__bf16*)(RegBig + 16920576);// [7808][1088]
    __bf16* T2   = (__bf16*)RegBig;             // [7808][1088]
    float*  Sb   = (float*)RegS;                // 64 * SBATCH
    float*  Eb   = (float*)RegS;                // [32*8*243*17]
    float*  S0   = (float*)(RegS + 4230144);    // [17][1088]
    float*  S1   = (float*)(RegS + 4304128);    // [17][1088]
    float* xout = (float*)d_out;
    float* mean_attn = xout + BND;

    dim3 blk(256);
    // 0) weight conversions to bf16 (padded)
    cvt_w<<<1664, blk, 0, stream>>>(w_qkv,   Wq,  1632, 544);
    cvt_w<<< 640, blk, 0, stream>>>(w_proj,  Wp,   544, 544);
    cvt_w<<<2176, blk, 0, stream>>>(mlp_w1,  Wm1, 2176, 544);
    cvt_w<<< 640, blk, 0, stream>>>(mlp_w2,  Wm2,  544, 2176);
    cvt_w<<<1152, blk, 0, stream>>>(w_trans, Wt,  1088, 544);
    cvt_w<<< 640, blk, 0, stream>>>(w_proj2, Wp2,  544, 1088);
    cvt_w<<<1152, blk, 0, stream>>>(emlp_w1, We1, 1088, 544);
    cvt_w<<< 640, blk, 0, stream>>>(emlp_w2, We2,  544, 1088);
    // 1) h = LN1(x) -> bf16
    ln_kernel<<<MROWS, blk, 0, stream>>>(x, ln1_g, ln1_b, Abf);
    // 2) qkv = h @ w_qkv^T -> bf16
    mgemm<0,0,0,1><<<dim3(13,61), blk, 0, stream>>>(Abf, Wq, nullptr, nullptr, Qkvb, MROWS, 1632, 544, 1632);
    // 3) attention -> o (Abf bf16), 4 passes of 64 (b,h)
    for (int p = 0; p < 4; p++) {
        attn_score<<<dim3(4,4,64), blk, 0, stream>>>(Qkvb, b_table, Sb, p * 64);
        attn_softmax<<<dim3(NTOK,64), blk, 0, stream>>>(Sb);
        attn_pv<<<dim3(2,4,64), blk, 0, stream>>>(Sb, Qkvb, Abf, p * 64);
    }
    // 4) x1 = x + o @ w_proj^T + b_proj -> F1
    mgemm<0,1,1,0><<<dim3(5,61), blk, 0, stream>>>(Abf, Wp, b_proj, x, F1, MROWS, 544, 544, 544);
    // 5) h2 = LN2(x1) -> bf16
    ln_kernel<<<MROWS, blk, 0, stream>>>(F1, ln2_g, ln2_b, Abf);
    // 6) t = gelu(h2 @ mlp_w1^T + b1) -> Tb bf16
    mgemm<1,1,0,1><<<dim3(17,61), blk, 0, stream>>>(Abf, Wm1, mlp_b1, nullptr, Tb, MROWS, 2176, 544, 2176);
    // 7) x2 = x1 + t @ mlp_w2^T + b2 -> F2
    mgemm<0,1,1,0><<<dim3(5,61), blk, 0, stream>>>(Tb, Wm2, mlp_b2, F1, F2, MROWS, 544, 2176, 544);
    // 8) h3 = eLN1(x2) -> bf16
    ln_kernel<<<MROWS, blk, 0, stream>>>(F2, eln1_g, eln1_b, Abf);
    // 9) xu = h3 @ w_trans^T + b_trans -> XU bf16
    mgemm<0,1,0,1><<<dim3(9,61), blk, 0, stream>>>(Abf, Wt, b_trans, nullptr, XU, MROWS, 1088, 544, 1088);
    // 10/11) s0, s1 (tiny fp32 GEMMs)
    gemm32_kernel<<<dim3(17,1), blk, 0, stream>>>(seed, w0, b0, S0, NSEED, UPDd, DIMd);
    gemm32_kernel<<<dim3(17,1), blk, 0, stream>>>(seed, w1, b1, S1, NSEED, UPDd, DIMd);
    // 12) a_raw
    seed_a_kernel<<<dim3(NTOK,BSZd), blk, 0, stream>>>(XU, S0, Eb);
    // 13) softmax over f
    seed_softmax_f<<<dim3(NSEED,NH,BSZd), blk, 0, stream>>>(Eb);
    // 14) zero mean_attn
    zero_kernel<<<1, 32, 0, stream>>>(mean_attn, NSEED);
    // 15) normalize over n + mean_attn
    seed_norm_n<<<dim3(NH,BSZd), blk, 0, stream>>>(Eb, mean_attn);
    // 16) o2 = a @ s1 -> O2 bf16
    seed_o2_kernel<<<dim3(NTOK,BSZd), blk, 0, stream>>>(Eb, S1, O2);
    // 17) x3 = x2 + o2 @ w_proj2^T + b_proj2 -> F1
    mgemm<0,1,1,0><<<dim3(5,61), blk, 0, stream>>>(O2, Wp2, b_proj2, F2, F1, MROWS, 544, 1088, 544);
    // 18) h4 = eLN2(x3) -> bf16
    ln_kernel<<<MROWS, blk, 0, stream>>>(F1, eln2_g, eln2_b, Abf);
    // 19) t2 = gelu(h4 @ emlp_w1^T + b1) -> T2 bf16
    mgemm<1,1,0,1><<<dim3(9,61), blk, 0, stream>>>(Abf, We1, emlp_b1, nullptr, T2, MROWS, 1088, 544, 1088);
    // 20) x4 = x3 + t2 @ emlp_w2^T + b2 -> d_out fp32
    mgemm<0,1,1,0><<<dim3(5,61), blk, 0, stream>>>(T2, We2, emlp_b2, F1, xout, MROWS, 544, 1088, 544);
}